// Round 4
// baseline (238.324 us; speedup 1.0000x reference)
//
#include <hip/hip_runtime.h>

// Adaptive embedding, 3-stage: partition -> pre-pack bf16 MFMA fragments -> LDS-free GEMM.
// out[tok,:] = 32 * emb_c[id] @ proj_c^T
//
// d_in[0] ids i32[16384]; (emb_i f32[*,d_i], proj_i f32[1024,d_i]) d_i=1024/256/64/16
// out f32[16384,1024].
//
// ws layout: [0,16) cnt[4]; [16, 262160) lists[4][16384];
//            [512K, +2.82MB) B_frag bf16; [4MB, +<=33.7MB) A_frag bf16.

constexpr int NTOK  = 16384;
constexpr int DPROJ = 1024;
constexpr float EMB_SCALE = 32.0f;

typedef __attribute__((ext_vector_type(8))) short short8;   // 8 bf16
typedef __attribute__((ext_vector_type(4))) float float4v;  // MFMA C/D

__device__ __forceinline__ short f2bf(float f) {  // RNE; inputs finite
    unsigned u = __builtin_bit_cast(unsigned, f);
    u += 0x7FFFu + ((u >> 16) & 1u);
    return (short)(u >> 16);
}

__global__ __launch_bounds__(256) void partition_kernel(
    const int* __restrict__ ids, int* __restrict__ cnt, int* __restrict__ lists)
{
    int t = blockIdx.x * 256 + threadIdx.x;
    int id = ids[t];
    int c = (id >= 200000) ? 3 : (id >= 40000) ? 2 : (id >= 20000) ? 1 : 0;
    int lane = threadIdx.x & 63;
    unsigned long long lt = (1ull << lane) - 1ull;
    int pos = 0;
#pragma unroll
    for (int i = 0; i < 4; ++i) {
        unsigned long long m = __ballot(c == i);
        int b = 0;
        if (lane == 0 && m) b = atomicAdd(&cnt[i], (int)__popcll(m));
        b = __shfl(b, 0);
        if (c == i) pos = b + (int)__popcll(m & lt);
    }
    lists[c * NTOK + pos] = t;
}

// ---- Fragment layout (verified via round-3 kernel, passed):
// A-frag: lane L = q*16 + r holds row r (of 16-row tile), k = kc*32 + q*8 + j.
// Address (bf16 units): base + tile16*(16*Dp) + kc*512 + L*8.
// B-frag identical with r = output-col % 16.

__global__ __launch_bounds__(256) void pack_proj(
    const float* __restrict__ p0, const float* __restrict__ p1,
    const float* __restrict__ p2, const float* __restrict__ p3,
    short* __restrict__ Bf)
{
    int t = blockIdx.x * 256 + threadIdx.x;
    int c, local;
    if      (t < 131072) { c = 0; local = t; }
    else if (t < 163840) { c = 1; local = t - 131072; }
    else if (t < 172032) { c = 2; local = t - 163840; }
    else if (t < 176128) { c = 3; local = t - 172032; }
    else return;
    constexpr int Dc[4] = {1024, 256, 64, 16};
    constexpr int Dp[4] = {1024, 256, 64, 32};
    constexpr int SS[4] = {7, 5, 3, 2};                       // log2(Dp/8)
    constexpr int BBase[4] = {0, 1048576, 1310720, 1376256};  // bf16 units
    const float* P[4] = {p0, p1, p2, p3};
    int ss = SS[c];
    int n = local >> ss;
    int s = local & ((1 << ss) - 1);
    int kc = s >> 2, q = s & 3;
    int k0 = kc * 32 + q * 8;
    int D = Dc[c], Dpad = Dp[c];
    const float* src = P[c] + (size_t)n * D + k0;
    short v[8];
#pragma unroll
    for (int j = 0; j < 8; ++j) v[j] = (k0 + j < D) ? f2bf(src[j]) : (short)0;
    size_t dst = (size_t)BBase[c] + (size_t)(n >> 4) * (16 * Dpad)
               + (size_t)kc * 512 + (q * 16 + (n & 15)) * 8;
    *(short8*)(Bf + dst) = *(const short8*)v;
}

__global__ __launch_bounds__(256) void pack_A(
    const int* __restrict__ ids, const int* __restrict__ cnt,
    const int* __restrict__ lists,
    const float* __restrict__ e0, const float* __restrict__ e1,
    const float* __restrict__ e2, const float* __restrict__ e3,
    short* __restrict__ Af)
{
    constexpr int Dc[4] = {1024, 256, 64, 16};
    constexpr int Dp[4] = {1024, 256, 64, 32};
    constexpr int SS[4] = {7, 5, 3, 2};
    constexpr int lo[4] = {0, 20000, 40000, 200000};
    const float* E[4] = {e0, e1, e2, e3};
    int cv[4], P[4], W[5]; W[0] = 0;
    size_t offA[4]; size_t a = 0;
#pragma unroll
    for (int c = 0; c < 4; ++c) {
        cv[c] = cnt[c];
        P[c]  = (cv[c] + 63) & ~63;
        W[c + 1] = W[c] + (P[c] << SS[c]);
        offA[c] = a; a += (size_t)P[c] * Dp[c];
    }
    int total = W[4];
    for (int t = blockIdx.x * 256 + threadIdx.x; t < total; t += gridDim.x * 256) {
        int c = (t >= W[1]) + (t >= W[2]) + (t >= W[3]);
        int local = t - W[c];
        int ss = SS[c];
        int i = local >> ss;
        int s = local & ((1 << ss) - 1);
        int kc = s >> 2, q = s & 3;
        int k0 = kc * 32 + q * 8;
        int D = Dc[c], Dpad = Dp[c];
        short v[8];
        if (i < cv[c]) {
            int tok = lists[c * NTOK + i];
            int row = ids[tok] - lo[c];
            const float* src = E[c] + (size_t)row * D + k0;
#pragma unroll
            for (int j = 0; j < 8; ++j) v[j] = (k0 + j < D) ? f2bf(src[j]) : (short)0;
        } else {
#pragma unroll
            for (int j = 0; j < 8; ++j) v[j] = 0;   // zero-pad rows [cnt, pad64)
        }
        size_t dst = offA[c] + (size_t)(i >> 4) * (16 * Dpad)
                   + (size_t)kc * 512 + (q * 16 + (i & 15)) * 8;
        *(short8*)(Af + dst) = *(const short8*)v;
    }
}

// Per-wave 64x64 tile; K-loop is pure global dwordx4 -> MFMA, no LDS/barriers.
template<int DP>
__device__ __forceinline__ void gemm_cluster(
    const short* __restrict__ Af, const short* __restrict__ Bf,
    const int* __restrict__ list, int count,
    float* __restrict__ out, int* toks)
{
    const int x = blockIdx.x, y = blockIdx.y;
    if (x * 256 >= count) return;
    const int tid = threadIdx.x;
    { int i = x * 256 + tid; toks[tid] = (i < count) ? list[i] : -1; }
    __syncthreads();
    const int w = tid >> 6, lane = tid & 63, col = lane & 15, quad = lane >> 4;
    const int m0 = x * 256 + w * 64;
    if (m0 >= count) return;                       // after barrier: safe
    constexpr int CH = DP / 32;
    const short* Ab = Af + (size_t)(m0 >> 4) * (16 * DP) + lane * 8;
    const short* Bb = Bf + (size_t)(y * 4) * (16 * DP) + lane * 8;
    float4v acc[4][4] = {};
#pragma unroll 2
    for (int kc = 0; kc < CH; ++kc) {
        short8 af[4], bf[4];
#pragma unroll
        for (int m = 0; m < 4; ++m)
            af[m] = *(const short8*)(Ab + (size_t)m * (16 * DP) + (size_t)kc * 512);
#pragma unroll
        for (int n = 0; n < 4; ++n)
            bf[n] = *(const short8*)(Bb + (size_t)n * (16 * DP) + (size_t)kc * 512);
#pragma unroll
        for (int m = 0; m < 4; ++m)
#pragma unroll
            for (int n = 0; n < 4; ++n)
                acc[m][n] = __builtin_amdgcn_mfma_f32_16x16x32_bf16(af[m], bf[n], acc[m][n], 0, 0, 0);
    }
#pragma unroll
    for (int m = 0; m < 4; ++m)
#pragma unroll
        for (int r = 0; r < 4; ++r) {
            int tok = toks[w * 64 + m * 16 + quad * 4 + r];
            if (tok < 0) continue;
            float* op = out + (size_t)tok * DPROJ + y * 64 + col;
#pragma unroll
            for (int n = 0; n < 4; ++n)
                op[n * 16] = acc[m][n][r] * EMB_SCALE;
        }
}

__global__ __launch_bounds__(256) void gemm_frag(
    const int* __restrict__ cnt, const int* __restrict__ lists,
    const short* __restrict__ Af, const short* __restrict__ Bf,
    float* __restrict__ out)
{
    __shared__ int toks[256];
    int P0 = (cnt[0] + 63) & ~63, P1 = (cnt[1] + 63) & ~63, P2 = (cnt[2] + 63) & ~63;
    switch (blockIdx.z) {
    case 0: gemm_cluster<1024>(Af, Bf, lists, cnt[0], out, toks); break;
    case 1: gemm_cluster<256>(Af + (size_t)P0 * 1024, Bf + 1048576,
                              lists + NTOK, cnt[1], out, toks); break;
    case 2: gemm_cluster<64>(Af + (size_t)P0 * 1024 + (size_t)P1 * 256, Bf + 1310720,
                             lists + 2 * NTOK, cnt[2], out, toks); break;
    case 3: gemm_cluster<32>(Af + (size_t)P0 * 1024 + (size_t)P1 * 256 + (size_t)P2 * 64,
                             Bf + 1376256, lists + 3 * NTOK, cnt[3], out, toks); break;
    }
}

// ---------------- Fallback (verified round-3 path) if ws too small ----------------
template<int D>
__device__ __forceinline__ void gemm_tile_fb(
    const int* __restrict__ ids, const float* __restrict__ emb,
    const float* __restrict__ proj, const int* __restrict__ list,
    int count, int lo, float* __restrict__ out,
    short (*Asm)[40], short (*Bsm)[40], int* smTok, int* smRow)
{
    const int m0 = blockIdx.y * 64;
    if (m0 >= count) return;
    const int n0 = blockIdx.x * 128;
    const int tid = threadIdx.x, lane = tid & 63, wv = tid >> 6;
    const int col = lane & 15, quad = lane >> 4;
    if (tid < 64) {
        int m = m0 + tid;
        int tok = (m < count) ? list[m] : -1;
        smTok[tid] = tok;
        smRow[tid] = (tok >= 0) ? (ids[tok] - lo) : 0;
    }
    __syncthreads();
    const int ar = tid >> 2, ac = (tid & 3) * 8;
    const int br = tid >> 1, bc = (tid & 1) * 16;
    const float* arow = emb  + (size_t)smRow[ar] * D + ac;
    const float* brow = proj + (size_t)(n0 + br) * D + bc;
    float4v acc[4][2] = {};
    constexpr int CHUNKS = (D + 31) / 32;
    for (int kc = 0; kc < CHUNKS; ++kc) {
        const int k0 = kc * 32;
        float4 a0 = {}, a1 = {}, b0 = {}, b1 = {}, b2 = {}, b3 = {};
        if (D >= 32 || ac < D)      a0 = *(const float4*)(arow + k0);
        if (D >= 32 || ac + 4 < D)  a1 = *(const float4*)(arow + k0 + 4);
        if (D >= 32 || bc < D)      b0 = *(const float4*)(brow + k0);
        if (D >= 32 || bc + 4 < D)  b1 = *(const float4*)(brow + k0 + 4);
        if (D >= 32 || bc + 8 < D)  b2 = *(const float4*)(brow + k0 + 8);
        if (D >= 32 || bc + 12 < D) b3 = *(const float4*)(brow + k0 + 12);
        if (D == 16) {
            if (ac >= 16) { a0 = float4{}; a1 = float4{}; }
            if (bc >= 16) { b0 = float4{}; b1 = float4{}; b2 = float4{}; b3 = float4{}; }
        }
        __syncthreads();
        short8 va = { f2bf(a0.x), f2bf(a0.y), f2bf(a0.z), f2bf(a0.w),
                      f2bf(a1.x), f2bf(a1.y), f2bf(a1.z), f2bf(a1.w) };
        *(short8*)&Asm[ar][ac] = va;
        short8 vb0 = { f2bf(b0.x), f2bf(b0.y), f2bf(b0.z), f2bf(b0.w),
                       f2bf(b1.x), f2bf(b1.y), f2bf(b1.z), f2bf(b1.w) };
        short8 vb1 = { f2bf(b2.x), f2bf(b2.y), f2bf(b2.z), f2bf(b2.w),
                       f2bf(b3.x), f2bf(b3.y), f2bf(b3.z), f2bf(b3.w) };
        *(short8*)&Bsm[br][bc] = vb0;
        *(short8*)&Bsm[br][bc + 8] = vb1;
        __syncthreads();
        short8 af[4], bf[2];
#pragma unroll
        for (int m = 0; m < 4; ++m) af[m] = *(const short8*)&Asm[m * 16 + col][quad * 8];
#pragma unroll
        for (int n = 0; n < 2; ++n) bf[n] = *(const short8*)&Bsm[wv * 32 + n * 16 + col][quad * 8];
#pragma unroll
        for (int m = 0; m < 4; ++m)
#pragma unroll
            for (int n = 0; n < 2; ++n)
                acc[m][n] = __builtin_amdgcn_mfma_f32_16x16x32_bf16(af[m], bf[n], acc[m][n], 0, 0, 0);
    }
#pragma unroll
    for (int m = 0; m < 4; ++m)
#pragma unroll
        for (int r = 0; r < 4; ++r) {
            int tok = smTok[m * 16 + quad * 4 + r];
            if (tok < 0) continue;
            float* op = out + (size_t)tok * DPROJ + n0 + wv * 32 + col;
            op[0]  = acc[m][0][r] * EMB_SCALE;
            op[16] = acc[m][1][r] * EMB_SCALE;
        }
}

__global__ __launch_bounds__(256) void adaptive_emb_gemm_fb(
    const int* __restrict__ ids,
    const float* __restrict__ e0, const float* __restrict__ p0,
    const float* __restrict__ e1, const float* __restrict__ p1,
    const float* __restrict__ e2, const float* __restrict__ p2,
    const float* __restrict__ e3, const float* __restrict__ p3,
    const int* __restrict__ cnt, const int* __restrict__ lists,
    float* __restrict__ out)
{
    __shared__ short Asm[64][40];
    __shared__ short Bsm[128][40];
    __shared__ int smTok[64];
    __shared__ int smRow[64];
    switch (blockIdx.z) {
    case 0: gemm_tile_fb<1024>(ids, e0, p0, lists,          cnt[0], 0,      out, Asm, Bsm, smTok, smRow); break;
    case 1: gemm_tile_fb<256> (ids, e1, p1, lists + NTOK,   cnt[1], 20000,  out, Asm, Bsm, smTok, smRow); break;
    case 2: gemm_tile_fb<64>  (ids, e2, p2, lists + 2*NTOK, cnt[2], 40000,  out, Asm, Bsm, smTok, smRow); break;
    case 3: gemm_tile_fb<16>  (ids, e3, p3, lists + 3*NTOK, cnt[3], 200000, out, Asm, Bsm, smTok, smRow); break;
    }
}

extern "C" void kernel_launch(void* const* d_in, const int* in_sizes, int n_in,
                              void* d_out, int out_size, void* d_ws, size_t ws_size,
                              hipStream_t stream) {
    const int*   ids = (const int*)d_in[0];
    const float* e0  = (const float*)d_in[1];
    const float* p0  = (const float*)d_in[2];
    const float* e1  = (const float*)d_in[3];
    const float* p1  = (const float*)d_in[4];
    const float* e2  = (const float*)d_in[5];
    const float* p2  = (const float*)d_in[6];
    const float* e3  = (const float*)d_in[7];
    const float* p3  = (const float*)d_in[8];
    float* out = (float*)d_out;

    int* cnt   = (int*)d_ws;
    int* lists = cnt + 4;

    hipMemsetAsync(cnt, 0, 16, stream);
    partition_kernel<<<dim3(NTOK / 256), 256, 0, stream>>>(ids, cnt, lists);

    if (ws_size >= (size_t)40 * 1024 * 1024) {
        short* Bf = (short*)((char*)d_ws + (512u << 10));
        short* Af = (short*)((char*)d_ws + (4u << 20));
        pack_proj<<<dim3(688), 256, 0, stream>>>(p0, p1, p2, p3, Bf);
        pack_A<<<dim3(1024), 256, 0, stream>>>(ids, cnt, lists, e0, e1, e2, e3, Af);
        gemm_frag<<<dim3(64, 16, 4), 256, 0, stream>>>(cnt, lists, Af, Bf, out);
    } else {
        adaptive_emb_gemm_fb<<<dim3(8, 256, 4), 256, 0, stream>>>(
            ids, e0, p0, e1, p1, e2, p2, e3, p3, cnt, lists, out);
    }
}